// Round 6
// baseline (274.619 us; speedup 1.0000x reference)
//
#include <hip/hip_runtime.h>
#include <hip/hip_bf16.h>

#define B_   64
#define T_   4096
#define K_   67
#define F_   134     // 2K input features
#define FP_  160     // padded to 5 K-tiles of 32
#define D_   256
#define C_   7
#define THR_ 0.1f
#define EPS_ 1e-5f
#define GRID_ 1024   // persistent: 4 blocks/CU x 256 CUs

typedef __bf16 bf16x8 __attribute__((ext_vector_type(8)));
typedef float  f32x4  __attribute__((ext_vector_type(4)));

typedef __attribute__((address_space(1))) const unsigned int guint;
typedef __attribute__((address_space(3))) unsigned int luint;

// ws layout:
//   [0, 65536)        pooled f32 [64][256]  (memset to 0 each launch)
//   [65536, +81920)   W1bf bf16 [256][160]  (d-major, f contiguous, padded)
//   [147456, +16384)  list u16 [<=8192]     (valid (b,x) tiles, compacted, b-major)
//   [163840, +4)      count int

__device__ __forceinline__ int get_len(const int* L, int b) {
    // defensive: harness may store int64 (odd words zero since 1<=len<=4096)
    return (L[1] == 0) ? L[2 * b] : L[b];
}

// tiled transpose, both sides coalesced
__global__ void convert_w1(const float* __restrict__ W1, __bf16* __restrict__ W1bf) {
    __shared__ float tile[32][33];
    const int d0 = blockIdx.x * 32, f0 = blockIdx.y * 32;
    const int tx = threadIdx.x & 31, ty = threadIdx.x >> 5;   // ty 0..7
#pragma unroll
    for (int r = 0; r < 32; r += 8) {
        int f = f0 + ty + r;
        tile[ty + r][tx] = (f < F_) ? W1[f * D_ + d0 + tx] : 0.f;
    }
    __syncthreads();
#pragma unroll
    for (int r = 0; r < 32; r += 8) {
        int d = d0 + ty + r;
        W1bf[d * FP_ + f0 + tx] = (__bf16)tile[tx][ty + r];
    }
}

// compacted list of valid 32-t tiles: entry = (b<<7) | x, x = t0/32; b-major order
__global__ void build_tiles(const int* __restrict__ L,
                            unsigned short* __restrict__ list,
                            int* __restrict__ count) {
    __shared__ int pref[65];
    const int tid = threadIdx.x;
    if (tid == 0) {
        int acc = 0;
        pref[0] = 0;
        for (int b = 0; b < B_; b++) {
            int len = (L[1] == 0) ? L[2 * b] : L[b];
            acc += (len + 31) >> 5;
            pref[b + 1] = acc;
        }
        *count = acc;
    }
    __syncthreads();
    const int total = pref[64];
    for (int i = tid; i < total; i += blockDim.x) {
        int lo = 0, hi = 64;                      // largest b with pref[b] <= i
        while (hi - lo > 1) { int mid = (lo + hi) >> 1;
                              if (pref[mid] <= i) lo = mid; else hi = mid; }
        list[i] = (unsigned short)((lo << 7) | (i - pref[lo]));
    }
}

// Persistent, chunked: block j owns a CONTIGUOUS slice of the b-major tile
// list. runmax accumulates in registers across tiles; atomic flush only on
// b-change / loop end (kills cross-XCD atomic line ping-pong).
__global__ __launch_bounds__(256, 4)
void fused_mlp_pool(const float* __restrict__ body,
                    const float* __restrict__ hr,
                    const float* __restrict__ hl,
                    const int*   __restrict__ length,
                    const float* __restrict__ b1,
                    const __bf16* __restrict__ W1bf,
                    const unsigned short* __restrict__ list,
                    const int* __restrict__ count,
                    float* __restrict__ pooled)
{
    __shared__ __align__(16) float  raw[6432];     // 25728 B: body|hr|hl slabs
    __shared__ __align__(16) __bf16 As[10 * 512];  // 10240 B: packed A tile
    __shared__ int len_s[B_];

    const int tid  = threadIdx.x;
    const int wave = tid >> 6;
    const int lane = tid & 63;
    const int quad = lane >> 4;
    const int l16  = lane & 15;
    const int dbase = wave * 64;

    if (tid < B_) len_s[tid] = get_len(length, tid);

    // B fragments + bias: once per block (loop-resident)
    bf16x8 bfrag[4][5];
    float  b1v[4];
#pragma unroll
    for (int n = 0; n < 4; n++) {
        int d = dbase + n * 16 + l16;
        const __bf16* p = W1bf + d * FP_ + quad * 8;
#pragma unroll
        for (int kt = 0; kt < 5; kt++)
            bfrag[n][kt] = *(const bf16x8*)(p + kt * 32);
        b1v[n] = b1[d];
    }

    // zero K-pad region of As once: k-pairs 67..79, 32 t (never overwritten)
    for (int i = tid; i < 416; i += 256) {
        int t = i & 31, kp = 67 + (i >> 5);
        int w = ((t >> 4) * 5 + (kp >> 4)) * 256 + (((kp >> 2) & 3) * 16 + (t & 15)) * 4 + (kp & 3);
        ((unsigned int*)As)[w] = 0u;
    }

    const int total = *count;
    const int chunk = (total + GRID_ - 1) / GRID_;
    const int ibeg  = blockIdx.x * chunk;
    const int iend  = min(ibeg + chunk, total);

    int   curb = -1;
    float runmax[4] = {0.f, 0.f, 0.f, 0.f};

    for (int i = ibeg; i < iend; i++) {
        const int e  = list[i];                   // uniform scalar load
        const int b  = e >> 7;
        const int t0 = (e & 127) << 5;

        if (b != curb) {
            if (curb >= 0) {                      // flush previous b
#pragma unroll
                for (int n = 0; n < 4; n++) {
                    float r = runmax[n];
                    r = fmaxf(r, __shfl_xor(r, 16, 64));
                    r = fmaxf(r, __shfl_xor(r, 32, 64));
                    if (quad == n)
                        atomicMax((unsigned int*)(pooled + curb * D_ + dbase + n * 16 + l16),
                                  __float_as_uint(r));
                }
            }
            curb = b;
            runmax[0] = runmax[1] = runmax[2] = runmax[3] = 0.f;
        }

        const long rowb = (long)b * T_;
        const float* bodyt = body + (rowb + t0) * 75;   // 9600 B, 16-aligned
        const float* hrt   = hr   + (rowb + t0) * 63;   // 8064 B, 16-aligned
        const float* hlt   = hl   + (rowb + t0) * 63;

        // ---- async global->LDS DMA, 1024 B per wave-issue ----
        for (int k = wave; k < 9; k += 4)
            __builtin_amdgcn_global_load_lds(
                (guint*)(bodyt + k * 256 + lane * 4),
                (luint*)((char*)raw + k * 1024 + lane * 16), 16, 0, 0);
        for (int k = wave; k < 7; k += 4)
            __builtin_amdgcn_global_load_lds(
                (guint*)(hrt + k * 256 + lane * 4),
                (luint*)((char*)raw + 9600 + k * 1024 + lane * 16), 16, 0, 0);
        for (int k = wave; k < 7; k += 4)
            __builtin_amdgcn_global_load_lds(
                (guint*)(hlt + k * 256 + lane * 4),
                (luint*)((char*)raw + 17664 + k * 1024 + lane * 16), 16, 0, 0);

        // slab tails (384 + 896 + 896 B) as one float4 per thread
        if (tid < 136) {
            const float* g; int loff;             // dword offsets
            if (tid < 24)      { g = bodyt + 2304 + tid * 4;        loff = 2304 + tid * 4; }
            else if (tid < 80) { g = hrt + 1792 + (tid - 24) * 4;   loff = 4192 + (tid - 24) * 4; }
            else               { g = hlt + 1792 + (tid - 80) * 4;   loff = 6208 + (tid - 80) * 4; }
            *(float4*)(raw + loff) = *(const float4*)g;
        }
        __syncthreads();   // drain DMA/tails; also fences prev tile's As reads

        // ---- repack: gate by conf, fp32->bf16, MFMA-A layout ----
#pragma unroll
        for (int it = 0; it < 8; it++) {
            int idx = it * 256 + tid;                 // 2048 = 32 t x 64 k
            int t = (((idx >> 5) & 3) << 3) | ((idx >> 2) & 7);
            int k = (((idx >> 7) & 15) << 2) | (idx & 3);
            int roff;
            if (k < 25)      roff = t * 75 + 3 * k;
            else if (k < 46) roff = 2400 + t * 63 + 3 * (k - 25);
            else             roff = 4416 + t * 63 + 3 * (k - 46);
            float x = raw[roff], y = raw[roff + 1], cf = raw[roff + 2];
            if (!(cf > THR_)) { x = 0.f; y = 0.f; }
            unsigned short ux = __builtin_bit_cast(unsigned short, (__bf16)x);
            unsigned short uy = __builtin_bit_cast(unsigned short, (__bf16)y);
            int w = ((t >> 4) * 5 + (k >> 4)) * 256 + (((k >> 2) & 3) * 16 + (t & 15)) * 4 + (k & 3);
            ((unsigned int*)As)[w] = (unsigned int)ux | ((unsigned int)uy << 16);
        }
        if (tid < 96) {                               // cleanup k = 64..66
            int t = tid & 31, k = 64 + (tid >> 5);
            int roff = 4416 + t * 63 + 3 * (k - 46);
            float x = raw[roff], y = raw[roff + 1], cf = raw[roff + 2];
            if (!(cf > THR_)) { x = 0.f; y = 0.f; }
            unsigned short ux = __builtin_bit_cast(unsigned short, (__bf16)x);
            unsigned short uy = __builtin_bit_cast(unsigned short, (__bf16)y);
            int w = ((t >> 4) * 5 + (k >> 4)) * 256 + (((k >> 2) & 3) * 16 + (t & 15)) * 4 + (k & 3);
            ((unsigned int*)As)[w] = (unsigned int)ux | ((unsigned int)uy << 16);
        }
        __syncthreads();

        // ---- MFMA: 32t x 256d, K = 160 ----
        f32x4 acc[2][4];
#pragma unroll
        for (int m = 0; m < 2; m++)
#pragma unroll
            for (int n = 0; n < 4; n++)
                acc[m][n] = (f32x4){0.f, 0.f, 0.f, 0.f};

#pragma unroll
        for (int kt = 0; kt < 5; kt++) {
#pragma unroll
            for (int m = 0; m < 2; m++) {
                bf16x8 a = *(const bf16x8*)(As + (m * 5 + kt) * 512 + lane * 8);
#pragma unroll
                for (int n = 0; n < 4; n++)
                    acc[m][n] = __builtin_amdgcn_mfma_f32_16x16x32_bf16(a, bfrag[n][kt], acc[m][n], 0, 0, 0);
            }
        }

        // ---- epilogue: bias + relu + validity -> register runmax only ----
        const int len = len_s[b];
#pragma unroll
        for (int m = 0; m < 2; m++) {
            int trow0 = t0 + m * 16 + quad * 4;
#pragma unroll
            for (int r = 0; r < 4; r++) {
                bool valid = (trow0 + r) < len;
#pragma unroll
                for (int n = 0; n < 4; n++) {
                    float v = acc[m][n][r] + b1v[n];
                    v = (v > 0.f) ? v : 0.f;          // forces +0, never -0
                    runmax[n] = (valid && v > runmax[n]) ? v : runmax[n];
                }
            }
        }
    }

    // final flush
    if (curb >= 0) {
#pragma unroll
        for (int n = 0; n < 4; n++) {
            float r = runmax[n];
            r = fmaxf(r, __shfl_xor(r, 16, 64));
            r = fmaxf(r, __shfl_xor(r, 32, 64));
            if (quad == n)
                atomicMax((unsigned int*)(pooled + curb * D_ + dbase + n * 16 + l16),
                          __float_as_uint(r));        // all values >= +0
        }
    }
}

__global__ void bn_classifier(const float* __restrict__ pooled,
                              const float* __restrict__ gamma,
                              const float* __restrict__ beta,
                              const float* __restrict__ Wc,
                              const float* __restrict__ bc,
                              float* __restrict__ out)
{
    __shared__ float scale_s[D_], shift_s[D_];
    const int tid = threadIdx.x;   // == d for stats
    float s = 0.f, ss = 0.f;
#pragma unroll 8
    for (int b = 0; b < B_; b++) {
        float v = pooled[b * D_ + tid];   // coalesced
        s += v; ss += v * v;
    }
    float mean = s * (1.f / B_);
    float var  = ss * (1.f / B_) - mean * mean;
    var = fmaxf(var, 0.f);
    float sc = gamma[tid] * rsqrtf(var + EPS_);
    scale_s[tid] = sc;
    shift_s[tid] = beta[tid] - mean * sc;

    const int wv = tid >> 6, ln = tid & 63;
    float wcr[4][C_];
#pragma unroll
    for (int j = 0; j < 4; j++)
#pragma unroll
        for (int c = 0; c < C_; c++)
            wcr[j][c] = Wc[(ln * 4 + j) * C_ + c];
    __syncthreads();

    for (int b = wv * 16; b < wv * 16 + 16; b++) {
        float4 v = *(const float4*)(pooled + b * D_ + ln * 4);   // coalesced
        float q[4];
        q[0] = v.x * scale_s[ln * 4 + 0] + shift_s[ln * 4 + 0];
        q[1] = v.y * scale_s[ln * 4 + 1] + shift_s[ln * 4 + 1];
        q[2] = v.z * scale_s[ln * 4 + 2] + shift_s[ln * 4 + 2];
        q[3] = v.w * scale_s[ln * 4 + 3] + shift_s[ln * 4 + 3];
        float p[C_];
#pragma unroll
        for (int c = 0; c < C_; c++) p[c] = 0.f;
#pragma unroll
        for (int j = 0; j < 4; j++)
#pragma unroll
            for (int c = 0; c < C_; c++)
                p[c] += q[j] * wcr[j][c];
#pragma unroll
        for (int c = 0; c < C_; c++) {
#pragma unroll
            for (int off = 1; off < 64; off <<= 1)
                p[c] += __shfl_xor(p[c], off, 64);
        }
        if (ln == 0) {
#pragma unroll
            for (int c = 0; c < C_; c++)
                out[b * C_ + c] = p[c] + bc[c];
        }
    }
}

extern "C" void kernel_launch(void* const* d_in, const int* in_sizes, int n_in,
                              void* d_out, int out_size, void* d_ws, size_t ws_size,
                              hipStream_t stream) {
    const float* body   = (const float*)d_in[0];
    const float* hr     = (const float*)d_in[1];
    const float* hl     = (const float*)d_in[2];
    const int*   length = (const int*)  d_in[3];
    const float* W1     = (const float*)d_in[4];
    const float* b1     = (const float*)d_in[5];
    const float* gamma  = (const float*)d_in[6];
    const float* beta   = (const float*)d_in[7];
    const float* Wc     = (const float*)d_in[8];
    const float* bc     = (const float*)d_in[9];
    float* out = (float*)d_out;

    float*          pooled = (float*)d_ws;
    __bf16*         W1bf   = (__bf16*)((char*)d_ws + 65536);
    unsigned short* list   = (unsigned short*)((char*)d_ws + 147456);
    int*            count  = (int*)((char*)d_ws + 163840);

    hipMemsetAsync(d_ws, 0, 65536, stream);                    // pooled = 0 (relu >= 0)
    convert_w1<<<dim3(8, 5), dim3(256), 0, stream>>>(W1, W1bf);
    build_tiles<<<dim3(1), dim3(256), 0, stream>>>(length, list, count);
    fused_mlp_pool<<<dim3(GRID_), dim3(256), 0, stream>>>(body, hr, hl, length, b1,
                                                          W1bf, list, count, pooled);
    bn_classifier<<<dim3(1), dim3(256), 0, stream>>>(pooled, gamma, beta, Wc, bc, out);
}

// Round 7
// 242.361 us; speedup vs baseline: 1.1331x; 1.1331x over previous
//
#include <hip/hip_runtime.h>
#include <hip/hip_bf16.h>

#define B_   64
#define T_   4096
#define K_   67
#define F_   134     // 2K input features
#define FP_  160     // padded to 5 K-tiles of 32
#define D_   256
#define C_   7
#define THR_ 0.1f
#define EPS_ 1e-5f

typedef __bf16 bf16x8 __attribute__((ext_vector_type(8)));
typedef float  f32x4  __attribute__((ext_vector_type(4)));

typedef __attribute__((address_space(1))) const unsigned int guint;
typedef __attribute__((address_space(3))) unsigned int luint;

// ws layout:
//   [0, 65536)        pooled f32 [64][256]  (memset to 0 each launch)
//   [65536, +81920)   W1bf bf16 [256][160]  (d-major, f contiguous, padded)

__device__ __forceinline__ int get_len(const int* L, int b) {
    // defensive: harness may store int64 (odd words zero since 1<=len<=4096)
    return (L[1] == 0) ? L[2 * b] : L[b];
}

// tiled transpose, both sides coalesced
__global__ void convert_w1(const float* __restrict__ W1, __bf16* __restrict__ W1bf) {
    __shared__ float tile[32][33];
    const int d0 = blockIdx.x * 32, f0 = blockIdx.y * 32;
    const int tx = threadIdx.x & 31, ty = threadIdx.x >> 5;   // ty 0..7
#pragma unroll
    for (int r = 0; r < 32; r += 8) {
        int f = f0 + ty + r;
        tile[ty + r][tx] = (f < F_) ? W1[f * D_ + d0 + tx] : 0.f;
    }
    __syncthreads();
#pragma unroll
    for (int r = 0; r < 32; r += 8) {
        int d = d0 + ty + r;
        W1bf[d * FP_ + f0 + tx] = (__bf16)tile[tx][ty + r];
    }
}

// One 32-t tile per block, R4 dispatch-order streaming (L3-friendly).
// B-fragments streamed from L2 inside the MFMA loop (no 80-reg hoist)
// -> small register footprint -> 4 blocks/CU.
__global__ __launch_bounds__(256, 4)
void fused_mlp_pool(const float* __restrict__ body,
                    const float* __restrict__ hr,
                    const float* __restrict__ hl,
                    const int*   __restrict__ length,
                    const float* __restrict__ b1,
                    const __bf16* __restrict__ W1bf,
                    float* __restrict__ pooled)
{
    const int b = blockIdx.y;
    const int len = get_len(length, b);
    const int t0 = blockIdx.x * 32;
    if (t0 >= len) return;

    __shared__ __align__(16) float  raw[6432];     // 25728 B: body|hr|hl slabs
    __shared__ __align__(16) __bf16 As[10 * 512];  // 10240 B: packed A tile

    const int tid  = threadIdx.x;
    const int wave = tid >> 6;
    const int lane = tid & 63;
    const int quad = lane >> 4;
    const int l16  = lane & 15;
    const int dbase = wave * 64;

    const long rowb = (long)b * T_;
    const float* bodyt = body + (rowb + t0) * 75;   // 9600 B, 16-aligned
    const float* hrt   = hr   + (rowb + t0) * 63;   // 8064 B, 16-aligned
    const float* hlt   = hl   + (rowb + t0) * 63;

    // ---- async global->LDS DMA, 1024 B per wave-issue ----
    for (int k = wave; k < 9; k += 4)
        __builtin_amdgcn_global_load_lds(
            (guint*)(bodyt + k * 256 + lane * 4),
            (luint*)((char*)raw + k * 1024 + lane * 16), 16, 0, 0);
    for (int k = wave; k < 7; k += 4)
        __builtin_amdgcn_global_load_lds(
            (guint*)(hrt + k * 256 + lane * 4),
            (luint*)((char*)raw + 9600 + k * 1024 + lane * 16), 16, 0, 0);
    for (int k = wave; k < 7; k += 4)
        __builtin_amdgcn_global_load_lds(
            (guint*)(hlt + k * 256 + lane * 4),
            (luint*)((char*)raw + 17664 + k * 1024 + lane * 16), 16, 0, 0);

    // slab tails (384 + 896 + 896 B) as one float4 per thread
    if (tid < 136) {
        const float* g; int loff;             // dword offsets
        if (tid < 24)      { g = bodyt + 2304 + tid * 4;        loff = 2304 + tid * 4; }
        else if (tid < 80) { g = hrt + 1792 + (tid - 24) * 4;   loff = 4192 + (tid - 24) * 4; }
        else               { g = hlt + 1792 + (tid - 80) * 4;   loff = 6208 + (tid - 80) * 4; }
        *(float4*)(raw + loff) = *(const float4*)g;
    }

    // zero K-pad region of As: k-pairs 67..79, 32 t (never overwritten)
    for (int i = tid; i < 416; i += 256) {
        int t = i & 31, kp = 67 + (i >> 5);
        int w = ((t >> 4) * 5 + (kp >> 4)) * 256 + (((kp >> 2) & 3) * 16 + (t & 15)) * 4 + (kp & 3);
        ((unsigned int*)As)[w] = 0u;
    }
    __syncthreads();   // drain DMA + tail/pad writes

    // ---- repack: gate by conf, fp32->bf16, MFMA-A layout ----
#pragma unroll
    for (int it = 0; it < 8; it++) {
        int idx = it * 256 + tid;                 // 2048 = 32 t x 64 k
        int t = (((idx >> 5) & 3) << 3) | ((idx >> 2) & 7);
        int k = (((idx >> 7) & 15) << 2) | (idx & 3);
        int roff;
        if (k < 25)      roff = t * 75 + 3 * k;
        else if (k < 46) roff = 2400 + t * 63 + 3 * (k - 25);
        else             roff = 4416 + t * 63 + 3 * (k - 46);
        float x = raw[roff], y = raw[roff + 1], cf = raw[roff + 2];
        if (!(cf > THR_)) { x = 0.f; y = 0.f; }
        unsigned short ux = __builtin_bit_cast(unsigned short, (__bf16)x);
        unsigned short uy = __builtin_bit_cast(unsigned short, (__bf16)y);
        int w = ((t >> 4) * 5 + (k >> 4)) * 256 + (((k >> 2) & 3) * 16 + (t & 15)) * 4 + (k & 3);
        ((unsigned int*)As)[w] = (unsigned int)ux | ((unsigned int)uy << 16);
    }
    if (tid < 96) {                               // cleanup k = 64..66
        int t = tid & 31, k = 64 + (tid >> 5);
        int roff = 4416 + t * 63 + 3 * (k - 46);
        float x = raw[roff], y = raw[roff + 1], cf = raw[roff + 2];
        if (!(cf > THR_)) { x = 0.f; y = 0.f; }
        unsigned short ux = __builtin_bit_cast(unsigned short, (__bf16)x);
        unsigned short uy = __builtin_bit_cast(unsigned short, (__bf16)y);
        int w = ((t >> 4) * 5 + (k >> 4)) * 256 + (((k >> 2) & 3) * 16 + (t & 15)) * 4 + (k & 3);
        ((unsigned int*)As)[w] = (unsigned int)ux | ((unsigned int)uy << 16);
    }
    __syncthreads();

    // ---- MFMA: 32t x 256d, K = 160; B-frags streamed from L2-hot W1bf ----
    f32x4 acc[2][4];
#pragma unroll
    for (int m = 0; m < 2; m++)
#pragma unroll
        for (int n = 0; n < 4; n++)
            acc[m][n] = (f32x4){0.f, 0.f, 0.f, 0.f};

    // wave reads rows d = dbase + n*16 + l16; per (kt,n): 16 rows x 64 B segs
    const __bf16* wb = W1bf + (dbase + l16) * FP_ + quad * 8;
#pragma unroll
    for (int kt = 0; kt < 5; kt++) {
        bf16x8 a0 = *(const bf16x8*)(As + (0 * 5 + kt) * 512 + lane * 8);
        bf16x8 a1 = *(const bf16x8*)(As + (1 * 5 + kt) * 512 + lane * 8);
#pragma unroll
        for (int n = 0; n < 4; n++) {
            bf16x8 bf = *(const bf16x8*)(wb + n * 16 * FP_ + kt * 32);
            acc[0][n] = __builtin_amdgcn_mfma_f32_16x16x32_bf16(a0, bf, acc[0][n], 0, 0, 0);
            acc[1][n] = __builtin_amdgcn_mfma_f32_16x16x32_bf16(a1, bf, acc[1][n], 0, 0, 0);
        }
    }

    // ---- epilogue: bias + relu + validity + max -> atomic ----
    float b1v[4];
#pragma unroll
    for (int n = 0; n < 4; n++) b1v[n] = b1[dbase + n * 16 + l16];

    float runmax[4] = {0.f, 0.f, 0.f, 0.f};
#pragma unroll
    for (int m = 0; m < 2; m++) {
        int trow0 = t0 + m * 16 + quad * 4;
#pragma unroll
        for (int r = 0; r < 4; r++) {
            bool valid = (trow0 + r) < len;
#pragma unroll
            for (int n = 0; n < 4; n++) {
                float v = acc[m][n][r] + b1v[n];
                v = (v > 0.f) ? v : 0.f;          // forces +0, never -0
                runmax[n] = (valid && v > runmax[n]) ? v : runmax[n];
            }
        }
    }
#pragma unroll
    for (int n = 0; n < 4; n++) {
        float r = runmax[n];
        r = fmaxf(r, __shfl_xor(r, 16, 64));
        r = fmaxf(r, __shfl_xor(r, 32, 64));
        if (quad == n) {
            atomicMax((unsigned int*)(pooled + b * D_ + dbase + n * 16 + l16),
                      __float_as_uint(r));        // all values >= +0
        }
    }
}

__global__ void bn_classifier(const float* __restrict__ pooled,
                              const float* __restrict__ gamma,
                              const float* __restrict__ beta,
                              const float* __restrict__ Wc,
                              const float* __restrict__ bc,
                              float* __restrict__ out)
{
    __shared__ float scale_s[D_], shift_s[D_];
    const int tid = threadIdx.x;   // == d for stats
    float s = 0.f, ss = 0.f;
#pragma unroll 8
    for (int b = 0; b < B_; b++) {
        float v = pooled[b * D_ + tid];   // coalesced
        s += v; ss += v * v;
    }
    float mean = s * (1.f / B_);
    float var  = ss * (1.f / B_) - mean * mean;
    var = fmaxf(var, 0.f);
    float sc = gamma[tid] * rsqrtf(var + EPS_);
    scale_s[tid] = sc;
    shift_s[tid] = beta[tid] - mean * sc;

    const int wv = tid >> 6, ln = tid & 63;
    float wcr[4][C_];
#pragma unroll
    for (int j = 0; j < 4; j++)
#pragma unroll
        for (int c = 0; c < C_; c++)
            wcr[j][c] = Wc[(ln * 4 + j) * C_ + c];
    __syncthreads();

    for (int b = wv * 16; b < wv * 16 + 16; b++) {
        float4 v = *(const float4*)(pooled + b * D_ + ln * 4);   // coalesced
        float q[4];
        q[0] = v.x * scale_s[ln * 4 + 0] + shift_s[ln * 4 + 0];
        q[1] = v.y * scale_s[ln * 4 + 1] + shift_s[ln * 4 + 1];
        q[2] = v.z * scale_s[ln * 4 + 2] + shift_s[ln * 4 + 2];
        q[3] = v.w * scale_s[ln * 4 + 3] + shift_s[ln * 4 + 3];
        float p[C_];
#pragma unroll
        for (int c = 0; c < C_; c++) p[c] = 0.f;
#pragma unroll
        for (int j = 0; j < 4; j++)
#pragma unroll
            for (int c = 0; c < C_; c++)
                p[c] += q[j] * wcr[j][c];
#pragma unroll
        for (int c = 0; c < C_; c++) {
#pragma unroll
            for (int off = 1; off < 64; off <<= 1)
                p[c] += __shfl_xor(p[c], off, 64);
        }
        if (ln == 0) {
#pragma unroll
            for (int c = 0; c < C_; c++)
                out[b * C_ + c] = p[c] + bc[c];
        }
    }
}

extern "C" void kernel_launch(void* const* d_in, const int* in_sizes, int n_in,
                              void* d_out, int out_size, void* d_ws, size_t ws_size,
                              hipStream_t stream) {
    const float* body   = (const float*)d_in[0];
    const float* hr     = (const float*)d_in[1];
    const float* hl     = (const float*)d_in[2];
    const int*   length = (const int*)  d_in[3];
    const float* W1     = (const float*)d_in[4];
    const float* b1     = (const float*)d_in[5];
    const float* gamma  = (const float*)d_in[6];
    const float* beta   = (const float*)d_in[7];
    const float* Wc     = (const float*)d_in[8];
    const float* bc     = (const float*)d_in[9];
    float* out = (float*)d_out;

    float*  pooled = (float*)d_ws;
    __bf16* W1bf   = (__bf16*)((char*)d_ws + 65536);

    hipMemsetAsync(d_ws, 0, 65536, stream);                    // pooled = 0 (relu >= 0)
    convert_w1<<<dim3(8, 5), dim3(256), 0, stream>>>(W1, W1bf);
    fused_mlp_pool<<<dim3(128, B_), dim3(256), 0, stream>>>(body, hr, hl, length, b1,
                                                            W1bf, pooled);
    bn_classifier<<<dim3(1), dim3(256), 0, stream>>>(pooled, gamma, beta, Wc, bc, out);
}